// Round 9
// baseline (231.127 us; speedup 1.0000x reference)
//
#include <hip/hip_runtime.h>
#include <math.h>

// Problem constants (fixed by setup_inputs / SPATIAL)
#define NB 2
#define NQ 12240
#define NH 8
#define NL 4
#define NK 4
#define VLEN 12240
#define M_TOT (NB * NQ)        // 24480 rows (== B*VLEN)
#define MT (M_TOT / 16)        // 1530 fragment-row tiles (exact)

typedef __attribute__((ext_vector_type(4))) float f32x4;
typedef __attribute__((ext_vector_type(8))) short bf16x8;
typedef __attribute__((ext_vector_type(8))) unsigned short u16x8;

__device__ __forceinline__ ushort f2bf(float x) {
    union { float f; unsigned u; } v; v.f = x;
    unsigned r = v.u + 0x7fffu + ((v.u >> 16) & 1u);
    return (ushort)(r >> 16);
}
__device__ __forceinline__ float bf2f(ushort h) {
    union { unsigned u; float f; } v; v.u = ((unsigned)h) << 16; return v.f;
}

// ---------------------------------------------------------------------------
// Weight preconversion only (A operands are now converted in-register inside
// the GEMMs — kills the 100 MB A-plane round trip of rounds 4-8).
// B-fragment layout: tile (nt,kt), lane l holds W[kt*32+(l>>4)*8+j][nt*16+(l&15)]
//   at ((nt*8+kt)*64+l)*8 + j.
// Bp offsets (ushorts): fused query plane H: Woff@0, Wattn@65536 (contiguous
//   nt 0..23); L: Woff@98304, Wattn@163840; WvH@196608 (WvL@262144 unused);
//   WoutH@327680 WoutL@393216.
// ---------------------------------------------------------------------------
__global__ __launch_bounds__(256) void preconv_B(
    const float* __restrict__ Woff, const float* __restrict__ Wattn,
    const float* __restrict__ Wv,   const float* __restrict__ Wout,
    ushort* __restrict__ Bp)
{
    const int gg = blockIdx.x * 256 + threadIdx.x;   // 0..28671
    const float* W; ushort* H; ushort* L; int N, tl;
    if (gg < 8192)       { W = Woff;  H = Bp + 0;      L = Bp + 98304;  N = 256; tl = gg; }
    else if (gg < 12288) { W = Wattn; H = Bp + 65536;  L = Bp + 163840; N = 128; tl = gg - 8192; }
    else if (gg < 20480) { W = Wv;    H = Bp + 196608; L = Bp + 262144; N = 256; tl = gg - 12288; }
    else                 { W = Wout;  H = Bp + 327680; L = Bp + 393216; N = 256; tl = gg - 20480; }
    const int l  = tl & 63;
    const int kt = (tl >> 6) & 7;
    const int nt = tl >> 9;
    const int colb = nt * 16 + (l & 15);
    const int krow = kt * 32 + ((l >> 4) << 3);
    ushort h8[8], l8[8];
    #pragma unroll
    for (int j = 0; j < 8; ++j) {
        float x = W[(size_t)(krow + j) * N + colb];
        h8[j] = f2bf(x);
        l8[j] = f2bf(x - bf2f(h8[j]));
    }
    *(ushort4*)(H + (size_t)tl * 8)     = *(ushort4*)&h8[0];
    *(ushort4*)(H + (size_t)tl * 8 + 4) = *(ushort4*)&h8[4];
    *(ushort4*)(L + (size_t)tl * 8)     = *(ushort4*)&l8[0];
    *(ushort4*)(L + (size_t)tl * 8 + 4) = *(ushort4*)&l8[4];
}

// ---------------------------------------------------------------------------
// MERGED query-logits + value-projection GEMM. Grid 3060 x 384 threads.
//   bid < 1530 : query path. A = queries (fp32, converted to hi/lo bf16
//     in-register), 3-term bf16x3, N=384 over 6 waves. Fused epilogue:
//     waves 0-3 -> tanh+ref+clamp -> pixel locs; waves 4-5 -> softmax
//     (16-lane shfl_xor reduce, exp without max-sub: |logit|<=~2) -> weights.
//   bid >= 1530: value path. A = value (fp32 -> bf16 hi in-register),
//     1-term, N=256 over waves 0-3 (waves 4-5 exit). Writes bf16 v plane.
// ---------------------------------------------------------------------------
__global__ __launch_bounds__(384) void gemm_qv(
    const float* __restrict__ Qf, const float* __restrict__ Vf,
    const ushort* __restrict__ Bp,
    const float* __restrict__ bias, const float* __restrict__ bias2,
    const float* __restrict__ ref,
    float* __restrict__ locC, float* __restrict__ attC,
    ushort* __restrict__ vC)
{
    const int wave = threadIdx.x >> 6;
    const int lane = threadIdx.x & 63;
    const bool isV = (blockIdx.x >= MT);
    const int mt   = isV ? (blockIdx.x - MT) : blockIdx.x;
    if (isV && wave >= 4) return;
    const int nt0 = wave * 4;
    const int lr = lane & 15, r0g = (lane >> 4) * 4;
    const int rowb = mt * 16 + r0g;

    const float* Af = (isV ? Vf : Qf) + (size_t)(mt * 16 + lr) * 256 + ((lane >> 4) << 3);

    f32x4 acc[4] = {};

    if (!isV) {
        const ushort* BH = Bp;            // fused [Woff|Wattn] hi, nt 0..23
        const ushort* BL = Bp + 98304;    // fused lo
        #pragma unroll
        for (int kt = 0; kt < 8; ++kt) {
            float4 a0 = *(const float4*)(Af + kt * 32);
            float4 a1 = *(const float4*)(Af + kt * 32 + 4);
            union { bf16x8 v; ushort u[8]; } ah, al;
            #pragma unroll
            for (int j = 0; j < 4; ++j) {
                float x = (&a0.x)[j];
                ushort hv = f2bf(x);
                ah.u[j] = hv; al.u[j] = f2bf(x - bf2f(hv));
            }
            #pragma unroll
            for (int j = 0; j < 4; ++j) {
                float x = (&a1.x)[j];
                ushort hv = f2bf(x);
                ah.u[4 + j] = hv; al.u[4 + j] = f2bf(x - bf2f(hv));
            }
            bf16x8 bh[4], bl[4];
            #pragma unroll
            for (int fn = 0; fn < 4; ++fn) {
                size_t off = (((size_t)(nt0 + fn) * 8 + kt) * 64 + lane) * 8;
                bh[fn] = *(const bf16x8*)(BH + off);
                bl[fn] = *(const bf16x8*)(BL + off);
            }
            #pragma unroll
            for (int fn = 0; fn < 4; ++fn) {
                acc[fn] = __builtin_amdgcn_mfma_f32_16x16x32_bf16(ah.v, bh[fn], acc[fn], 0, 0, 0);
                acc[fn] = __builtin_amdgcn_mfma_f32_16x16x32_bf16(ah.v, bl[fn], acc[fn], 0, 0, 0);
                acc[fn] = __builtin_amdgcn_mfma_f32_16x16x32_bf16(al.v, bh[fn], acc[fn], 0, 0, 0);
            }
        }
        if (wave < 4) {
            // ---- offsets -> pixel locations ----
            #pragma unroll
            for (int fn = 0; fn < 4; ++fn) {
                const int c  = wave * 64 + fn * 16 + lr;     // 0..255
                const int l  = (c >> 3) & 3;                 // level
                const int xy = c & 1;
                const float sc = 0.5f * (float)(96 >> l) - 0.5f;
                const float b = bias[c];
                #pragma unroll
                for (int r = 0; r < 4; ++r) {
                    const int row = rowb + r;
                    const float rp = ref[(size_t)row * 8 + l * 2 + xy];
                    const float t  = tanhf(acc[fn][r] + b);
                    const float lc = fminf(fmaxf(rp + t, -1.f), 1.f);
                    locC[(size_t)row * 256 + c] = (lc + 1.f) * sc;
                }
            }
        } else {
            // ---- attn logits -> softmax weights (per 16-lane group) ----
            #pragma unroll
            for (int fn = 0; fn < 4; ++fn) {
                const int hcol = (wave - 4) * 64 + fn * 16 + lr;   // 0..127
                const float b = bias2[hcol];
                #pragma unroll
                for (int r = 0; r < 4; ++r) {
                    float e = expf(acc[fn][r] + b);
                    float s = e;
                    s += __shfl_xor(s, 1);
                    s += __shfl_xor(s, 2);
                    s += __shfl_xor(s, 4);
                    s += __shfl_xor(s, 8);
                    attC[(size_t)(rowb + r) * 128 + hcol] = e / s;
                }
            }
        }
    } else {
        const ushort* BH = Bp + 196608;   // Wv hi
        #pragma unroll
        for (int kt = 0; kt < 8; ++kt) {
            float4 a0 = *(const float4*)(Af + kt * 32);
            float4 a1 = *(const float4*)(Af + kt * 32 + 4);
            union { bf16x8 v; ushort u[8]; } ah;
            #pragma unroll
            for (int j = 0; j < 4; ++j) ah.u[j]     = f2bf((&a0.x)[j]);
            #pragma unroll
            for (int j = 0; j < 4; ++j) ah.u[4 + j] = f2bf((&a1.x)[j]);
            bf16x8 bh[4];
            #pragma unroll
            for (int fn = 0; fn < 4; ++fn) {
                size_t off = (((size_t)(nt0 + fn) * 8 + kt) * 64 + lane) * 8;
                bh[fn] = *(const bf16x8*)(BH + off);
            }
            #pragma unroll
            for (int fn = 0; fn < 4; ++fn)
                acc[fn] = __builtin_amdgcn_mfma_f32_16x16x32_bf16(ah.v, bh[fn], acc[fn], 0, 0, 0);
        }
        #pragma unroll
        for (int fn = 0; fn < 4; ++fn) {
            const int col = (nt0 + fn) * 16 + lr;
            #pragma unroll
            for (int r = 0; r < 4; ++r)
                vC[(size_t)(rowb + r) * 256 + col] = f2bf(acc[fn][r]);
        }
    }
}

// ---------------------------------------------------------------------------
// Sampling: block = 64 queries x 1 head (XCD-pinned: blockIdx%8 == head).
// Per gid 4 lanes x 8 channels (16B ushort8 corner loads). loc/att staged to
// LDS once, broadcast. Full unroll (r7 config, 54us) — r8 showed occupancy
// does NOT help this kernel (TA-scatter + VALU bound).
// Output written directly as the bf16 A-fragment plane for the output GEMM.
// ---------------------------------------------------------------------------
__global__ __launch_bounds__(256) void sample_kernel(
    const ushort* __restrict__ v_bf,  // (B, VLEN, 256) bf16
    const float* __restrict__ locs,   // (B*Q, 256) pixel coords
    const float* __restrict__ attnw,  // (B*Q, 128)
    ushort* __restrict__ AccH)
{
    __shared__ float sloc[64][36];
    __shared__ float satt[64][20];

    const int h   = blockIdx.x & 7;
    const int qc  = blockIdx.x >> 3;       // 0..382
    const int tid = threadIdx.x;

    #pragma unroll
    for (int i = 0; i < 2; ++i) {
        int idx = tid + i * 256;
        int row = idx >> 3;
        int c   = (idx & 7) * 4;
        int bqr = qc * 64 + row;
        float4 v = make_float4(0.f, 0.f, 0.f, 0.f);
        if (bqr < M_TOT) v = *(const float4*)(locs + (size_t)bqr * 256 + h * 32 + c);
        *(float4*)&sloc[row][c] = v;
    }
    {
        int row = tid >> 2;
        int c   = (tid & 3) * 4;
        int bqr = qc * 64 + row;
        float4 v = make_float4(0.f, 0.f, 0.f, 0.f);
        if (bqr < M_TOT) v = *(const float4*)(attnw + (size_t)bqr * 128 + h * 16 + c);
        *(float4*)&satt[row][c] = v;
    }
    __syncthreads();

    const int qi = tid >> 2;          // 0..63
    const int c8 = tid & 3;           // 8-channel group
    const int bq = qc * 64 + qi;
    const int b  = (bq >= NQ) ? 1 : 0;
    const ushort* vbase = v_bf + ((size_t)b * VLEN) * 256 + h * 32 + c8 * 8;

    float acc[8] = {};
    #pragma unroll
    for (int l = 0; l < NL; ++l) {
        const int Wl = 96 >> l;
        const int st = (l == 0) ? 0 : (l == 1) ? 9216 : (l == 2) ? 11520 : 12096;
        #pragma unroll
        for (int k = 0; k < NK; ++k) {
            float px = sloc[qi][(l * 4 + k) * 2 + 0];
            float py = sloc[qi][(l * 4 + k) * 2 + 1];
            float w  = satt[qi][l * 4 + k];
            float x0f = floorf(px), y0f = floorf(py);
            float wx = px - x0f, wy = py - y0f;
            int x0 = (int)x0f, y0 = (int)y0f;
            x0 = min(max(x0, 0), Wl - 1);
            y0 = min(max(y0, 0), Wl - 1);
            int x1 = min(x0 + 1, Wl - 1);
            int y1 = min(y0 + 1, Wl - 1);
            float w11 = w * wy * wx;
            float w10 = w * wy - w11;
            float w01 = w * wx - w11;
            float w00 = w - w01 - w10 - w11;
            const ushort* r0 = vbase + (size_t)(st + y0 * Wl) * 256;
            const ushort* r1 = vbase + (size_t)(st + y1 * Wl) * 256;
            u16x8 u00 = *(const u16x8*)(r0 + (size_t)x0 * 256);
            u16x8 u01 = *(const u16x8*)(r0 + (size_t)x1 * 256);
            u16x8 u10 = *(const u16x8*)(r1 + (size_t)x0 * 256);
            u16x8 u11 = *(const u16x8*)(r1 + (size_t)x1 * 256);
            #pragma unroll
            for (int j = 0; j < 8; ++j) {
                acc[j] += w00 * bf2f(u00[j]) + w01 * bf2f(u01[j])
                        + w10 * bf2f(u10[j]) + w11 * bf2f(u11[j]);
            }
        }
    }

    if (bq < M_TOT) {
        const int mt  = bq >> 4;
        const int lfr = (c8 << 4) | (bq & 15);
        const size_t base = (((size_t)mt * 8 + h) * 64 + lfr) * 8;
        u16x8 hh;
        #pragma unroll
        for (int j = 0; j < 8; ++j) hh[j] = f2bf(acc[j]);
        *(u16x8*)(AccH + base) = hh;
    }
}

// ---------------------------------------------------------------------------
// Output projection: acc(bf16 A-fragment plane) @ Wout -> fp32 out.
// 2-term (AhBh + AhBl). 1530 blocks x 256 threads.
// ---------------------------------------------------------------------------
__global__ __launch_bounds__(256) void gemm_out(
    const ushort* __restrict__ Ah,
    const ushort* __restrict__ Bh, const ushort* __restrict__ Bl,
    float* __restrict__ C)
{
    const int wave = threadIdx.x >> 6;
    const int lane = threadIdx.x & 63;
    const int mt   = blockIdx.x;
    const int nt0  = wave * 4;

    f32x4 acc[4] = {};
    const ushort* aH = Ah + ((size_t)mt * 8 * 64 + lane) * 8;

    #pragma unroll
    for (int kt = 0; kt < 8; ++kt) {
        bf16x8 ah = *(const bf16x8*)(aH + kt * 512);
        bf16x8 bh[4], bl[4];
        #pragma unroll
        for (int fn = 0; fn < 4; ++fn) {
            size_t off = (((size_t)(nt0 + fn) * 8 + kt) * 64 + lane) * 8;
            bh[fn] = *(const bf16x8*)(Bh + off);
            bl[fn] = *(const bf16x8*)(Bl + off);
        }
        #pragma unroll
        for (int fn = 0; fn < 4; ++fn) {
            acc[fn] = __builtin_amdgcn_mfma_f32_16x16x32_bf16(ah, bh[fn], acc[fn], 0, 0, 0);
            acc[fn] = __builtin_amdgcn_mfma_f32_16x16x32_bf16(ah, bl[fn], acc[fn], 0, 0, 0);
        }
    }

    const int lr = lane & 15, r0 = (lane >> 4) * 4;
    const int rowb = mt * 16 + r0;
    #pragma unroll
    for (int fn = 0; fn < 4; ++fn) {
        const int col = (nt0 + fn) * 16 + lr;
        #pragma unroll
        for (int r = 0; r < 4; ++r)
            C[(size_t)(rowb + r) * 256 + col] = acc[fn][r];
    }
}

// ---------------------------------------------------------------------------
extern "C" void kernel_launch(void* const* d_in, const int* in_sizes, int n_in,
                              void* d_out, int out_size, void* d_ws, size_t ws_size,
                              hipStream_t stream)
{
    const float* queries = (const float*)d_in[0];   // (B, Q, 256)
    const float* refpts  = (const float*)d_in[1];   // (B, Q, 4, 2)
    const float* value   = (const float*)d_in[2];   // (B, VLEN, 256)
    const float* Wv      = (const float*)d_in[3];   // (256, 256)
    const float* Woff    = (const float*)d_in[4];   // (256, 256)
    const float* boff    = (const float*)d_in[5];   // (256,)
    const float* Wattn   = (const float*)d_in[6];   // (256, 128)
    const float* battn   = (const float*)d_in[7];   // (128,)
    const float* Wout    = (const float*)d_in[8];   // (256, 256)
    float* out = (float*)d_out;                     // (B, Q, 256)

    char* ws = (char*)d_ws;
    float*  off_ws  = (float*)(ws);                 // 25,067,520 B  (pixel locs)
    float*  attn_ws = (float*)(ws + 25067520);      // 12,533,760 B  (softmax weights)
    ushort* v_bf    = (ushort*)(ws + 37601280);     // 12,533,760 B
    ushort* AccH    = (ushort*)(ws + 50135040);     // 12,533,760 B
    ushort* Bp      = (ushort*)(ws + 87736320);     //    917,504 B

    // 0) weights -> hi/lo B-fragment planes (tiny)
    preconv_B<<<112, 256, 0, stream>>>(Woff, Wattn, Wv, Wout, Bp);
    // 1) MERGED: query logits (fused tanh/ref/softmax epilogue) + value proj.
    //    A operands read directly from fp32 and converted in-register.
    gemm_qv<<<3060, 384, 0, stream>>>(queries, value, Bp, boff, battn, refpts,
                                      off_ws, attn_ws, v_bf);
    // 2) bilinear sampling -> bf16 A-fragment plane
    sample_kernel<<<3064, 256, 0, stream>>>(v_bf, off_ws, attn_ws, AccH);
    // 3) output projection: acc @ Wout -> d_out
    gemm_out<<<1530, 256, 0, stream>>>(AccH, Bp + 327680, Bp + 393216, out);
}

// Round 11
// 221.247 us; speedup vs baseline: 1.0447x; 1.0447x over previous
//
#include <hip/hip_runtime.h>
#include <math.h>

// Problem constants (fixed by setup_inputs / SPATIAL)
#define NB 2
#define NQ 12240
#define NH 8
#define NL 4
#define NK 4
#define VLEN 12240
#define M_TOT (NB * NQ)        // 24480 rows (== B*VLEN)
#define MT (M_TOT / 16)        // 1530 fragment-row tiles (exact)

typedef __attribute__((ext_vector_type(4))) float f32x4;
typedef __fp16 f16;
typedef __attribute__((ext_vector_type(8))) __fp16 f16x8;
typedef __attribute__((ext_vector_type(2))) __fp16 f16x2;

// Bp plane offsets (in f16 elements):
//   fused query [Woff nt0..15 | Wattn nt16..23] hi @ 0 (98304)
//   fused lo @ 98304 ; Wv (single f16) @ 196608 ; Wout (single f16) @ 262144
#define BP_FL 98304
#define BP_WV 196608
#define BP_WO 262144

// ---------------------------------------------------------------------------
// Weight preconversion (tiny): f16 hi/lo for query weights, single f16 for
// Wv / Wout. B-fragment layout: tile (nt,kt), lane l holds
// W[kt*32+(l>>4)*8+j][nt*16+(l&15)] at ((nt*8+kt)*64+l)*8 + j.
// ---------------------------------------------------------------------------
__global__ __launch_bounds__(256) void preconv_B(
    const float* __restrict__ Woff, const float* __restrict__ Wattn,
    const float* __restrict__ Wv,   const float* __restrict__ Wout,
    f16* __restrict__ Bp)
{
    const int gg = blockIdx.x * 256 + threadIdx.x;   // 0..28671
    const float* W; f16* H; f16* L; int N, tl; bool two;
    if (gg < 8192)       { W = Woff;  H = Bp;           L = Bp + BP_FL;         N = 256; tl = gg;         two = true;  }
    else if (gg < 12288) { W = Wattn; H = Bp + 65536;   L = Bp + BP_FL + 65536; N = 128; tl = gg - 8192;  two = true;  }
    else if (gg < 20480) { W = Wv;    H = Bp + BP_WV;   L = nullptr;            N = 256; tl = gg - 12288; two = false; }
    else                 { W = Wout;  H = Bp + BP_WO;   L = nullptr;            N = 256; tl = gg - 20480; two = false; }
    const int l  = tl & 63;
    const int kt = (tl >> 6) & 7;
    const int nt = tl >> 9;
    const int colb = nt * 16 + (l & 15);
    const int krow = kt * 32 + ((l >> 4) << 3);
    union { f16 f[8]; ushort4 u[2]; } h8, l8;
    #pragma unroll
    for (int j = 0; j < 8; ++j) {
        float x = W[(size_t)(krow + j) * N + colb];
        f16 hv = (f16)x;
        h8.f[j] = hv;
        l8.f[j] = (f16)(x - (float)hv);
    }
    *(ushort4*)(H + (size_t)tl * 8)     = h8.u[0];
    *(ushort4*)(H + (size_t)tl * 8 + 4) = h8.u[1];
    if (two) {
        *(ushort4*)(L + (size_t)tl * 8)     = l8.u[0];
        *(ushort4*)(L + (size_t)tl * 8 + 4) = l8.u[1];
    }
}

// ---------------------------------------------------------------------------
// MERGED query-logits + value-projection GEMM, f16, MROWS=2.
// Grid 1530 x 384 threads:
//   bid < 765 : query path, mt0=bid*2. A = queries fp32 -> f16 hi/lo via
//     v_cvt_pkrtz (1 inst per 2 elems). 3-term f16x3, N=384 over 6 waves.
//     Fused epilogue: waves 0-3 tanh+ref+clamp -> pixel locs; waves 4-5
//     softmax (16-lane shfl_xor; exp w/o max-sub, |logit|<=~2).
//   bid >= 765: value path, mt0=(bid-765)*2. 1-term f16 (10-bit mantissa),
//     waves 0-3 (N=256), waves 4-5 exit. Writes f16 v plane.
// launch_bounds(384,3): VGPR cap ~168 so all per-kt loads stay in flight
// (round 9: compiler picked 40 VGPR -> serialized loads -> MfmaUtil 8%).
// ---------------------------------------------------------------------------
__global__ __launch_bounds__(384, 3) void gemm_qv(
    const float* __restrict__ Qf, const float* __restrict__ Vf,
    const f16* __restrict__ Bp,
    const float* __restrict__ bias, const float* __restrict__ bias2,
    const float* __restrict__ ref,
    float* __restrict__ locC, float* __restrict__ attC,
    f16* __restrict__ vC)
{
    const int wave = threadIdx.x >> 6;
    const int lane = threadIdx.x & 63;
    const bool isV = (blockIdx.x >= 765);
    const int mt0  = (isV ? (blockIdx.x - 765) : blockIdx.x) * 2;
    if (isV && wave >= 4) return;
    const int nt0 = wave * 4;
    const int lr = lane & 15, r0g = (lane >> 4) * 4;

    const float* A0 = (isV ? Vf : Qf) + (size_t)(mt0 * 16 + lr) * 256 + ((lane >> 4) << 3);
    const float* A1 = A0 + 16 * 256;

    f32x4 acc[2][4] = {};

    if (!isV) {
        const f16* BH = Bp;
        const f16* BL = Bp + BP_FL;
        #pragma unroll
        for (int kt = 0; kt < 8; ++kt) {
            f16x8 bh[4], bl[4];
            #pragma unroll
            for (int fn = 0; fn < 4; ++fn) {
                size_t off = (((size_t)(nt0 + fn) * 8 + kt) * 64 + lane) * 8;
                bh[fn] = *(const f16x8*)(BH + off);
                bl[fn] = *(const f16x8*)(BL + off);
            }
            #pragma unroll
            for (int m = 0; m < 2; ++m) {
                const float* Af = m ? A1 : A0;
                float4 a0 = *(const float4*)(Af + kt * 32);
                float4 a1 = *(const float4*)(Af + kt * 32 + 4);
                union { f16x8 v; f16x2 h[4]; } ah, al;
                ah.h[0] = __builtin_amdgcn_cvt_pkrtz(a0.x, a0.y);
                ah.h[1] = __builtin_amdgcn_cvt_pkrtz(a0.z, a0.w);
                ah.h[2] = __builtin_amdgcn_cvt_pkrtz(a1.x, a1.y);
                ah.h[3] = __builtin_amdgcn_cvt_pkrtz(a1.z, a1.w);
                al.h[0] = __builtin_amdgcn_cvt_pkrtz(a0.x - (float)ah.h[0][0], a0.y - (float)ah.h[0][1]);
                al.h[1] = __builtin_amdgcn_cvt_pkrtz(a0.z - (float)ah.h[1][0], a0.w - (float)ah.h[1][1]);
                al.h[2] = __builtin_amdgcn_cvt_pkrtz(a1.x - (float)ah.h[2][0], a1.y - (float)ah.h[2][1]);
                al.h[3] = __builtin_amdgcn_cvt_pkrtz(a1.z - (float)ah.h[3][0], a1.w - (float)ah.h[3][1]);
                #pragma unroll
                for (int fn = 0; fn < 4; ++fn) {
                    acc[m][fn] = __builtin_amdgcn_mfma_f32_16x16x32_f16(ah.v, bh[fn], acc[m][fn], 0, 0, 0);
                    acc[m][fn] = __builtin_amdgcn_mfma_f32_16x16x32_f16(ah.v, bl[fn], acc[m][fn], 0, 0, 0);
                    acc[m][fn] = __builtin_amdgcn_mfma_f32_16x16x32_f16(al.v, bh[fn], acc[m][fn], 0, 0, 0);
                }
            }
        }
        #pragma unroll
        for (int m = 0; m < 2; ++m) {
            const int rowb = (mt0 + m) * 16 + r0g;
            if (wave < 4) {
                // ---- offsets -> pixel locations ----
                #pragma unroll
                for (int fn = 0; fn < 4; ++fn) {
                    const int c  = wave * 64 + fn * 16 + lr;     // 0..255
                    const int l  = (c >> 3) & 3;                 // level
                    const int xy = c & 1;
                    const float sc = 0.5f * (float)(96 >> l) - 0.5f;
                    const float b = bias[c];
                    #pragma unroll
                    for (int r = 0; r < 4; ++r) {
                        const int row = rowb + r;
                        const float rp = ref[(size_t)row * 8 + l * 2 + xy];
                        const float t  = tanhf(acc[m][fn][r] + b);
                        const float lc = fminf(fmaxf(rp + t, -1.f), 1.f);
                        locC[(size_t)row * 256 + c] = (lc + 1.f) * sc;
                    }
                }
            } else {
                // ---- attn logits -> softmax weights (per 16-lane group) ----
                #pragma unroll
                for (int fn = 0; fn < 4; ++fn) {
                    const int hcol = (wave - 4) * 64 + fn * 16 + lr;   // 0..127
                    const float b = bias2[hcol];
                    #pragma unroll
                    for (int r = 0; r < 4; ++r) {
                        float e = expf(acc[m][fn][r] + b);
                        float s = e;
                        s += __shfl_xor(s, 1);
                        s += __shfl_xor(s, 2);
                        s += __shfl_xor(s, 4);
                        s += __shfl_xor(s, 8);
                        attC[(size_t)(rowb + r) * 128 + hcol] = e / s;
                    }
                }
            }
        }
    } else {
        const f16* BH = Bp + BP_WV;
        #pragma unroll
        for (int kt = 0; kt < 8; ++kt) {
            f16x8 bh[4];
            #pragma unroll
            for (int fn = 0; fn < 4; ++fn) {
                size_t off = (((size_t)(nt0 + fn) * 8 + kt) * 64 + lane) * 8;
                bh[fn] = *(const f16x8*)(BH + off);
            }
            #pragma unroll
            for (int m = 0; m < 2; ++m) {
                const float* Af = m ? A1 : A0;
                float4 a0 = *(const float4*)(Af + kt * 32);
                float4 a1 = *(const float4*)(Af + kt * 32 + 4);
                union { f16x8 v; f16x2 h[4]; } ah;
                ah.h[0] = __builtin_amdgcn_cvt_pkrtz(a0.x, a0.y);
                ah.h[1] = __builtin_amdgcn_cvt_pkrtz(a0.z, a0.w);
                ah.h[2] = __builtin_amdgcn_cvt_pkrtz(a1.x, a1.y);
                ah.h[3] = __builtin_amdgcn_cvt_pkrtz(a1.z, a1.w);
                #pragma unroll
                for (int fn = 0; fn < 4; ++fn)
                    acc[m][fn] = __builtin_amdgcn_mfma_f32_16x16x32_f16(ah.v, bh[fn], acc[m][fn], 0, 0, 0);
            }
        }
        #pragma unroll
        for (int m = 0; m < 2; ++m) {
            const int rowb = (mt0 + m) * 16 + r0g;
            #pragma unroll
            for (int fn = 0; fn < 4; ++fn) {
                const int col = (nt0 + fn) * 16 + lr;
                #pragma unroll
                for (int r = 0; r < 4; ++r)
                    vC[(size_t)(rowb + r) * 256 + col] = (f16)acc[m][fn][r];
            }
        }
    }
}

// ---------------------------------------------------------------------------
// Sampling: block = 64 queries x 1 head (XCD-pinned: blockIdx%8 == head).
// Per gid 4 lanes x 8 channels (16B f16x8 corner loads). loc/att staged to
// LDS once, broadcast. Full unroll (r7 config, 54us — r8 showed bounding
// occupancy does NOT help; TA-scatter + VALU bound).
// Output written as the f16 A-fragment plane for the output GEMM (pkrtz).
// ---------------------------------------------------------------------------
__global__ __launch_bounds__(256) void sample_kernel(
    const f16* __restrict__ v_f16,   // (B, VLEN, 256) f16
    const float* __restrict__ locs,  // (B*Q, 256) pixel coords
    const float* __restrict__ attnw, // (B*Q, 128)
    f16* __restrict__ AccH)
{
    __shared__ float sloc[64][36];
    __shared__ float satt[64][20];

    const int h   = blockIdx.x & 7;
    const int qc  = blockIdx.x >> 3;       // 0..382
    const int tid = threadIdx.x;

    #pragma unroll
    for (int i = 0; i < 2; ++i) {
        int idx = tid + i * 256;
        int row = idx >> 3;
        int c   = (idx & 7) * 4;
        int bqr = qc * 64 + row;
        float4 v = make_float4(0.f, 0.f, 0.f, 0.f);
        if (bqr < M_TOT) v = *(const float4*)(locs + (size_t)bqr * 256 + h * 32 + c);
        *(float4*)&sloc[row][c] = v;
    }
    {
        int row = tid >> 2;
        int c   = (tid & 3) * 4;
        int bqr = qc * 64 + row;
        float4 v = make_float4(0.f, 0.f, 0.f, 0.f);
        if (bqr < M_TOT) v = *(const float4*)(attnw + (size_t)bqr * 128 + h * 16 + c);
        *(float4*)&satt[row][c] = v;
    }
    __syncthreads();

    const int qi = tid >> 2;          // 0..63
    const int c8 = tid & 3;           // 8-channel group
    const int bq = qc * 64 + qi;
    const int b  = (bq >= NQ) ? 1 : 0;
    const f16* vbase = v_f16 + ((size_t)b * VLEN) * 256 + h * 32 + c8 * 8;

    float acc[8] = {};
    #pragma unroll
    for (int l = 0; l < NL; ++l) {
        const int Wl = 96 >> l;
        const int st = (l == 0) ? 0 : (l == 1) ? 9216 : (l == 2) ? 11520 : 12096;
        #pragma unroll
        for (int k = 0; k < NK; ++k) {
            float px = sloc[qi][(l * 4 + k) * 2 + 0];
            float py = sloc[qi][(l * 4 + k) * 2 + 1];
            float w  = satt[qi][l * 4 + k];
            float x0f = floorf(px), y0f = floorf(py);
            float wx = px - x0f, wy = py - y0f;
            int x0 = (int)x0f, y0 = (int)y0f;
            x0 = min(max(x0, 0), Wl - 1);
            y0 = min(max(y0, 0), Wl - 1);
            int x1 = min(x0 + 1, Wl - 1);
            int y1 = min(y0 + 1, Wl - 1);
            float w11 = w * wy * wx;
            float w10 = w * wy - w11;
            float w01 = w * wx - w11;
            float w00 = w - w01 - w10 - w11;
            const f16* r0 = vbase + (size_t)(st + y0 * Wl) * 256;
            const f16* r1 = vbase + (size_t)(st + y1 * Wl) * 256;
            f16x8 u00 = *(const f16x8*)(r0 + (size_t)x0 * 256);
            f16x8 u01 = *(const f16x8*)(r0 + (size_t)x1 * 256);
            f16x8 u10 = *(const f16x8*)(r1 + (size_t)x0 * 256);
            f16x8 u11 = *(const f16x8*)(r1 + (size_t)x1 * 256);
            #pragma unroll
            for (int j = 0; j < 8; ++j) {
                acc[j] += w00 * (float)u00[j] + w01 * (float)u01[j]
                        + w10 * (float)u10[j] + w11 * (float)u11[j];
            }
        }
    }

    if (bq < M_TOT) {
        const int mt  = bq >> 4;
        const int lfr = (c8 << 4) | (bq & 15);
        const size_t base = (((size_t)mt * 8 + h) * 64 + lfr) * 8;
        union { f16x8 v; f16x2 h[4]; } hh;
        hh.h[0] = __builtin_amdgcn_cvt_pkrtz(acc[0], acc[1]);
        hh.h[1] = __builtin_amdgcn_cvt_pkrtz(acc[2], acc[3]);
        hh.h[2] = __builtin_amdgcn_cvt_pkrtz(acc[4], acc[5]);
        hh.h[3] = __builtin_amdgcn_cvt_pkrtz(acc[6], acc[7]);
        *(f16x8*)(AccH + base) = hh.v;
    }
}

// ---------------------------------------------------------------------------
// Output projection: acc(f16 A-fragment plane) @ Wout(f16) -> fp32 out.
// 1-term f16, MROWS=2. 765 blocks x 256 threads.
// ---------------------------------------------------------------------------
__global__ __launch_bounds__(256) void gemm_out(
    const f16* __restrict__ Ah, const f16* __restrict__ Bh,
    float* __restrict__ C)
{
    const int wave = threadIdx.x >> 6;
    const int lane = threadIdx.x & 63;
    const int mt0  = blockIdx.x * 2;
    const int nt0  = wave * 4;

    f32x4 acc[2][4] = {};
    const f16* aH0 = Ah + ((size_t)mt0 * 8 * 64 + lane) * 8;
    const f16* aH1 = aH0 + 8 * 64 * 8;

    #pragma unroll
    for (int kt = 0; kt < 8; ++kt) {
        f16x8 ah0 = *(const f16x8*)(aH0 + kt * 512);
        f16x8 ah1 = *(const f16x8*)(aH1 + kt * 512);
        f16x8 bh[4];
        #pragma unroll
        for (int fn = 0; fn < 4; ++fn) {
            size_t off = (((size_t)(nt0 + fn) * 8 + kt) * 64 + lane) * 8;
            bh[fn] = *(const f16x8*)(Bh + off);
        }
        #pragma unroll
        for (int fn = 0; fn < 4; ++fn) {
            acc[0][fn] = __builtin_amdgcn_mfma_f32_16x16x32_f16(ah0, bh[fn], acc[0][fn], 0, 0, 0);
            acc[1][fn] = __builtin_amdgcn_mfma_f32_16x16x32_f16(ah1, bh[fn], acc[1][fn], 0, 0, 0);
        }
    }

    const int lr = lane & 15, r0 = (lane >> 4) * 4;
    #pragma unroll
    for (int m = 0; m < 2; ++m) {
        const int rowb = (mt0 + m) * 16 + r0;
        #pragma unroll
        for (int fn = 0; fn < 4; ++fn) {
            const int col = (nt0 + fn) * 16 + lr;
            #pragma unroll
            for (int r = 0; r < 4; ++r)
                C[(size_t)(rowb + r) * 256 + col] = acc[m][fn][r];
        }
    }
}

// ---------------------------------------------------------------------------
extern "C" void kernel_launch(void* const* d_in, const int* in_sizes, int n_in,
                              void* d_out, int out_size, void* d_ws, size_t ws_size,
                              hipStream_t stream)
{
    const float* queries = (const float*)d_in[0];   // (B, Q, 256)
    const float* refpts  = (const float*)d_in[1];   // (B, Q, 4, 2)
    const float* value   = (const float*)d_in[2];   // (B, VLEN, 256)
    const float* Wv      = (const float*)d_in[3];   // (256, 256)
    const float* Woff    = (const float*)d_in[4];   // (256, 256)
    const float* boff    = (const float*)d_in[5];   // (256,)
    const float* Wattn   = (const float*)d_in[6];   // (256, 128)
    const float* battn   = (const float*)d_in[7];   // (128,)
    const float* Wout    = (const float*)d_in[8];   // (256, 256)
    float* out = (float*)d_out;                     // (B, Q, 256)

    char* ws = (char*)d_ws;
    float* off_ws  = (float*)(ws);                  // 25,067,520 B (pixel locs)
    float* attn_ws = (float*)(ws + 25067520);       // 12,533,760 B (softmax w)
    f16*   v_f16   = (f16*)(ws + 37601280);         // 12,533,760 B
    f16*   AccH    = (f16*)(ws + 50135040);         // 12,533,760 B
    f16*   Bp      = (f16*)(ws + 62668800);         //    655,360 B

    // 0) weights -> f16 fragment planes (tiny)
    preconv_B<<<112, 256, 0, stream>>>(Woff, Wattn, Wv, Wout, Bp);
    // 1) MERGED query logits (fused tanh/ref/softmax epilogue) + value proj
    gemm_qv<<<1530, 384, 0, stream>>>(queries, value, Bp, boff, battn, refpts,
                                      off_ws, attn_ws, v_f16);
    // 2) bilinear sampling -> f16 A-fragment plane
    sample_kernel<<<3064, 256, 0, stream>>>(v_f16, off_ws, attn_ws, AccH);
    // 3) output projection: acc @ Wout -> d_out
    gemm_out<<<765, 256, 0, stream>>>(AccH, Bp + BP_WO, out);
}